// Round 7
// baseline (1111.557 us; speedup 1.0000x reference)
//
#include <hip/hip_runtime.h>

#define N_NODES 100000
#define N_EDGES 1600000
#define IN_C 128
#define HID_C 64
#define OUT_C 32

#define NBUCK 782        // ceil(100000 / 128) buckets of 128 nodes
#define NBLK_B 1024      // edge-chunk blocks for bucket count/scatter
#define CHUNK 1563       // ceil(N_EDGES / NBLK_B)
#define BSTRIDE 1024     // padded stride for bcnt/off tables

#define GROWS 16         // rows per GEMM block
#define GEMM_BLKS 6250   // N_NODES / GROWS (exact)

typedef unsigned int uint;
typedef unsigned short ushort;

__device__ inline ushort f2bf(float f) {   // RNE float->bf16
    uint u = __float_as_uint(f);
    u += 0x7fff + ((u >> 16) & 1);
    return (ushort)(u >> 16);
}
__device__ inline float bf2f(ushort h) {
    return __uint_as_float(((uint)h) << 16);
}

// ---------------- K1: per-block coarse bucket histogram (LDS atomics only) ----------------

__global__ __launch_bounds__(256) void k_bucket_count(const int* __restrict__ dst,
                                                      int* __restrict__ bcnt) {
    __shared__ int h[NBUCK];
    int t = threadIdx.x;
    for (int b = t; b < NBUCK; b += 256) h[b] = 0;
    __syncthreads();
    int base = blockIdx.x * CHUNK;
    int end = base + CHUNK; if (end > N_EDGES) end = N_EDGES;
#pragma unroll
    for (int it = 0; it < 7; ++it) {
        int i = base + it * 256 + t;
        if (i < end) atomicAdd(&h[dst[i] >> 7], 1);
    }
    __syncthreads();
    for (int b = t; b < NBUCK; b += 256) bcnt[blockIdx.x * BSTRIDE + b] = h[b];
}

// ---------------- K2a: per-bucket column scan over 1024 blocks -> off, total ----------------

__global__ __launch_bounds__(256) void k_col_scan(const int* __restrict__ bcnt,
                                                  int* __restrict__ off,
                                                  int* __restrict__ total) {
    __shared__ int v[NBLK_B];
    __shared__ int ps[256];
    int t = threadIdx.x, b = blockIdx.x;
#pragma unroll
    for (int q = 0; q < NBLK_B / 256; ++q)
        v[q * 256 + t] = bcnt[(q * 256 + t) * BSTRIDE + b];
    __syncthreads();
    int l0 = v[t * 4], l1 = v[t * 4 + 1], l2 = v[t * 4 + 2], l3 = v[t * 4 + 3];
    ps[t] = l0 + l1 + l2 + l3;
    __syncthreads();
    for (int o = 1; o < 256; o <<= 1) {
        int u = (t >= o) ? ps[t - o] : 0;
        __syncthreads();
        ps[t] += u;
        __syncthreads();
    }
    int ex = (t > 0) ? ps[t - 1] : 0;
    off[(t * 4 + 0) * BSTRIDE + b] = ex; ex += l0;
    off[(t * 4 + 1) * BSTRIDE + b] = ex; ex += l1;
    off[(t * 4 + 2) * BSTRIDE + b] = ex; ex += l2;
    off[(t * 4 + 3) * BSTRIDE + b] = ex; ex += l3;
    if (t == 255) total[b] = ex;
}

// ---------------- K2b: scan bucket totals -> bucket_start ----------------

__global__ __launch_bounds__(256) void k_bucket_scan(const int* __restrict__ total,
                                                     int* __restrict__ bucket_start) {
    __shared__ int ps[256];
    int t = threadIdx.x;
    int v[4];
    int base = t * 4;
#pragma unroll
    for (int q = 0; q < 4; ++q) v[q] = (base + q < NBUCK) ? total[base + q] : 0;
    ps[t] = v[0] + v[1] + v[2] + v[3];
    __syncthreads();
    for (int o = 1; o < 256; o <<= 1) {
        int u = (t >= o) ? ps[t - o] : 0;
        __syncthreads();
        ps[t] += u;
        __syncthreads();
    }
    int run = (t > 0) ? ps[t - 1] : 0;
#pragma unroll
    for (int q = 0; q < 4; ++q) {
        if (base + q <= NBUCK) bucket_start[base + q] = run;
        run += v[q];
    }
}

// ------- K3 fat kernel: blocks [0,1024) scatter edges into buckets; rest do h1 = x@W1 -------

__global__ __launch_bounds__(256) void k_scatter_fat(const int* __restrict__ src,
                                                     const int* __restrict__ dst,
                                                     const int* __restrict__ bucket_start,
                                                     const int* __restrict__ off,
                                                     int* __restrict__ tmp,
                                                     const float* __restrict__ x,
                                                     const float* __restrict__ W1,
                                                     ushort* __restrict__ h1b) {
    __shared__ float smem[GROWS * IN_C];  // 8 KiB
    int t = threadIdx.x;
    if (blockIdx.x < NBLK_B) {
        // bucket scatter: write window per (block, bucket) is disjoint
        int* cur = (int*)smem;
        for (int b = t; b < NBUCK; b += 256)
            cur[b] = bucket_start[b] + off[blockIdx.x * BSTRIDE + b];
        __syncthreads();
        int base = blockIdx.x * CHUNK;
        int end = base + CHUNK; if (end > N_EDGES) end = N_EDGES;
#pragma unroll
        for (int it = 0; it < 7; ++it) {
            int i = base + it * 256 + t;
            if (i < end) {
                int s = src[i], d = dst[i];
                int b = d >> 7;
                int p = atomicAdd(&cur[b], 1);
                tmp[p] = (s << 7) | (d & 127);
            }
        }
    } else {
        // h1 = x @ W1, 16 rows/block; x tile in LDS, W1 streamed from L1/L2
        int rowbase = (blockIdx.x - NBLK_B) * GROWS;
#pragma unroll
        for (int q = 0; q < 8; ++q)
            smem[q * 256 + t] = x[rowbase * IN_C + q * 256 + t];
        __syncthreads();
        int wave = t >> 6, lane = t & 63;
        int rl0 = wave * 4;
        float a0 = 0.f, a1 = 0.f, a2 = 0.f, a3 = 0.f;
#pragma unroll 4
        for (int k = 0; k < IN_C; k += 4) {
            float4 x0 = *(const float4*)&smem[(rl0 + 0) * IN_C + k];
            float4 x1 = *(const float4*)&smem[(rl0 + 1) * IN_C + k];
            float4 x2 = *(const float4*)&smem[(rl0 + 2) * IN_C + k];
            float4 x3 = *(const float4*)&smem[(rl0 + 3) * IN_C + k];
            float w0 = W1[(k + 0) * HID_C + lane];
            float w1 = W1[(k + 1) * HID_C + lane];
            float w2 = W1[(k + 2) * HID_C + lane];
            float w3 = W1[(k + 3) * HID_C + lane];
            a0 += x0.x * w0 + x0.y * w1 + x0.z * w2 + x0.w * w3;
            a1 += x1.x * w0 + x1.y * w1 + x1.z * w2 + x1.w * w3;
            a2 += x2.x * w0 + x2.y * w1 + x2.z * w2 + x2.w * w3;
            a3 += x3.x * w0 + x3.y * w1 + x3.z * w2 + x3.w * w3;
        }
        int row = rowbase + rl0;
        h1b[(row + 0) * HID_C + lane] = f2bf(a0);
        h1b[(row + 1) * HID_C + lane] = f2bf(a1);
        h1b[(row + 2) * HID_C + lane] = f2bf(a2);
        h1b[(row + 3) * HID_C + lane] = f2bf(a3);
    }
}

// ---------------- K4: per-bucket degree -> dinv ----------------

__global__ __launch_bounds__(256) void k_deg(const int* __restrict__ bucket_start,
                                             const int* __restrict__ tmp,
                                             float* __restrict__ dinv) {
    __shared__ int h[128];
    int t = threadIdx.x, b = blockIdx.x;
    if (t < 128) h[t] = 0;
    __syncthreads();
    int e0 = bucket_start[b], e1 = bucket_start[b + 1];
    for (int e = e0 + t; e < e1; e += 256) atomicAdd(&h[tmp[e] & 127], 1);
    __syncthreads();
    int g = b * 128 + t;
    if (t < 128 && g < N_NODES) dinv[g] = rsqrtf((float)(h[t] + 1));  // +1 self loop
}

// ------- K5: per-bucket aggregate layer 1 + relu + fused @W2 -> hs2 (bf16) -------
// Block = 1024 thr (16 waves) per 128-node bucket. LDS acc [128][64] f32.

__global__ __launch_bounds__(1024) void k_agg1(const int* __restrict__ bucket_start,
                                               const int* __restrict__ tmp,
                                               const ushort* __restrict__ h1b,
                                               const float* __restrict__ dinv,
                                               const float* __restrict__ b1,
                                               const float* __restrict__ W2,
                                               ushort* __restrict__ hs2b) {
    __shared__ float acc[128 * HID_C];   // 32 KiB
    __shared__ float W2s[HID_C * OUT_C]; // 8 KiB
    __shared__ float b1s[HID_C];
    int t = threadIdx.x, b = blockIdx.x;
    for (int i = t; i < 128 * HID_C; i += 1024) acc[i] = 0.f;
    for (int i = t; i < HID_C * OUT_C; i += 1024) W2s[i] = W2[i];
    if (t < HID_C) b1s[t] = b1[t];
    __syncthreads();

    int e0 = bucket_start[b], e1 = bucket_start[b + 1];
    int wave = t >> 6, lane = t & 63;
    // 4 edges per wave per iteration for MLP
    for (int e = e0 + wave * 4; e < e1; e += 64) {
        int v0 = tmp[e];
        int v1 = (e + 1 < e1) ? tmp[e + 1] : -1;
        int v2 = (e + 2 < e1) ? tmp[e + 2] : -1;
        int v3 = (e + 3 < e1) ? tmp[e + 3] : -1;
        int s0 = v0 >> 7, s1 = v1 >> 7, s2 = v2 >> 7, s3 = v3 >> 7;
        float g0 = dinv[s0];
        float f0 = bf2f(h1b[s0 * HID_C + lane]);
        float g1 = 0.f, f1 = 0.f, g2 = 0.f, f2 = 0.f, g3 = 0.f, f3 = 0.f;
        if (v1 >= 0) { g1 = dinv[s1]; f1 = bf2f(h1b[s1 * HID_C + lane]); }
        if (v2 >= 0) { g2 = dinv[s2]; f2 = bf2f(h1b[s2 * HID_C + lane]); }
        if (v3 >= 0) { g3 = dinv[s3]; f3 = bf2f(h1b[s3 * HID_C + lane]); }
        atomicAdd(&acc[(v0 & 127) * HID_C + lane], g0 * f0);
        if (v1 >= 0) atomicAdd(&acc[(v1 & 127) * HID_C + lane], g1 * f1);
        if (v2 >= 0) atomicAdd(&acc[(v2 & 127) * HID_C + lane], g2 * f2);
        if (v3 >= 0) atomicAdd(&acc[(v3 & 127) * HID_C + lane], g3 * f3);
    }
    __syncthreads();

    int gbase = b * 128;
    // epilogue 1: a1 = relu(dn*(acc + dn*h1_self) + b1), in place in LDS
    for (int ln = wave; ln < 128; ln += 16) {
        int g = gbase + ln;
        if (g < N_NODES) {
            float dn = dinv[g];
            float self = bf2f(h1b[g * HID_C + lane]);
            float s = acc[ln * HID_C + lane] + dn * self;
            acc[ln * HID_C + lane] = fmaxf(dn * s + b1s[lane], 0.f);
        }
    }
    __syncthreads();
    // epilogue 2 (fused gemm2): hs2[g][o] = dinv[g] * sum_k a1[k] * W2[k][o]
    int half = lane >> 5, o = lane & 31;
    for (int ln = wave * 2 + half; ln < 128; ln += 32) {
        int g = gbase + ln;
        if (g >= N_NODES) continue;
        float dn = dinv[g];
        float sum = 0.f;
#pragma unroll 8
        for (int k = 0; k < HID_C; ++k)
            sum += acc[ln * HID_C + k] * W2s[k * OUT_C + o];
        hs2b[g * OUT_C + o] = f2bf(dn * sum);
    }
}

// ------- K6: per-bucket aggregate layer 2 + epilogue -> out -------
// Block = 1024 thr per bucket. LDS acc [128][32] f32. 32-lane group per edge.

__global__ __launch_bounds__(1024) void k_agg2(const int* __restrict__ bucket_start,
                                               const int* __restrict__ tmp,
                                               const ushort* __restrict__ hs2b,
                                               const float* __restrict__ dinv,
                                               const float* __restrict__ b2,
                                               float* __restrict__ out) {
    __shared__ float acc[128 * OUT_C];  // 16 KiB
    __shared__ float b2s[OUT_C];
    int t = threadIdx.x, b = blockIdx.x;
    for (int i = t; i < 128 * OUT_C; i += 1024) acc[i] = 0.f;
    if (t < OUT_C) b2s[t] = b2[t];
    __syncthreads();

    int e0 = bucket_start[b], e1 = bucket_start[b + 1];
    int grp = t >> 5;      // 0..31
    int o   = t & 31;
    for (int e = e0 + grp * 4; e < e1; e += 128) {
        int v0 = tmp[e];
        int v1 = (e + 1 < e1) ? tmp[e + 1] : -1;
        int v2 = (e + 2 < e1) ? tmp[e + 2] : -1;
        int v3 = (e + 3 < e1) ? tmp[e + 3] : -1;
        float f0 = bf2f(hs2b[(v0 >> 7) * OUT_C + o]);
        float f1 = 0.f, f2 = 0.f, f3 = 0.f;
        if (v1 >= 0) f1 = bf2f(hs2b[(v1 >> 7) * OUT_C + o]);
        if (v2 >= 0) f2 = bf2f(hs2b[(v2 >> 7) * OUT_C + o]);
        if (v3 >= 0) f3 = bf2f(hs2b[(v3 >> 7) * OUT_C + o]);
        atomicAdd(&acc[(v0 & 127) * OUT_C + o], f0);
        if (v1 >= 0) atomicAdd(&acc[(v1 & 127) * OUT_C + o], f1);
        if (v2 >= 0) atomicAdd(&acc[(v2 & 127) * OUT_C + o], f2);
        if (v3 >= 0) atomicAdd(&acc[(v3 & 127) * OUT_C + o], f3);
    }
    __syncthreads();

    int gbase = b * 128;
    for (int ln = grp; ln < 128; ln += 32) {
        int g = gbase + ln;
        if (g < N_NODES) {
            float dn = dinv[g];
            float self = bf2f(hs2b[g * OUT_C + o]);
            out[g * OUT_C + o] = dn * (acc[ln * OUT_C + o] + self) + b2s[o];
        }
    }
}

extern "C" void kernel_launch(void* const* d_in, const int* in_sizes, int n_in,
                              void* d_out, int out_size, void* d_ws, size_t ws_size,
                              hipStream_t stream) {
    const float* x  = (const float*)d_in[0];
    const int* ei   = (const int*)d_in[1];   // [2, E]: src then dst
    const float* W1 = (const float*)d_in[2];
    const float* b1 = (const float*)d_in[3];
    const float* W2 = (const float*)d_in[4];
    const float* b2 = (const float*)d_in[5];
    float* out = (float*)d_out;

    const int* src = ei;
    const int* dst = ei + N_EDGES;

    // workspace layout (bytes), total ~34.5 MB
    char* ws = (char*)d_ws;
    float*  dinv         = (float*)(ws + 0);          //   400,128
    int*    bucket_start = (int*)(ws + 400128);       //     4,096
    int*    total        = (int*)(ws + 404224);       //     4,096
    int*    bcnt         = (int*)(ws + 408320);       // 4,194,304
    int*    off          = (int*)(ws + 4602624);      // 4,194,304
    int*    tmp          = (int*)(ws + 8796928);      // 6,400,000
    ushort* h1b          = (ushort*)(ws + 15196928);  // 12,800,000 (bf16)
    ushort* hs2b         = (ushort*)(ws + 27996928);  //  6,400,000 (bf16)

    k_bucket_count<<<NBLK_B, 256, 0, stream>>>(dst, bcnt);
    k_col_scan<<<NBUCK, 256, 0, stream>>>(bcnt, off, total);
    k_bucket_scan<<<1, 256, 0, stream>>>(total, bucket_start);

    k_scatter_fat<<<NBLK_B + GEMM_BLKS, 256, 0, stream>>>(src, dst, bucket_start, off,
                                                          tmp, x, W1, h1b);
    k_deg<<<NBUCK, 256, 0, stream>>>(bucket_start, tmp, dinv);

    k_agg1<<<NBUCK, 1024, 0, stream>>>(bucket_start, tmp, h1b, dinv, b1, W2, hs2b);
    k_agg2<<<NBUCK, 1024, 0, stream>>>(bucket_start, tmp, hs2b, dinv, b2, out);
}

// Round 8
// 193.434 us; speedup vs baseline: 5.7464x; 5.7464x over previous
//
#include <hip/hip_runtime.h>

#define N_NODES 100000
#define N_EDGES 1600000
#define IN_C 128
#define HID_C 64
#define OUT_C 32

#define NBUCK 782        // ceil(100000 / 128) buckets of 128 nodes
#define NBLK_B 1024      // edge-chunk blocks for bucket count/scatter
#define CHUNK 1563       // ceil(N_EDGES / NBLK_B)
#define BSTRIDE 1024     // padded stride for bcnt/off tables
#define MAXPT 12         // per-thread reg capacity in CSR build (3072/bucket)

#define GROWS 16         // rows per GEMM block
#define GEMM_BLKS 6250   // N_NODES / GROWS (exact)

typedef unsigned int uint;
typedef unsigned short ushort;

__device__ inline ushort f2bf(float f) {   // RNE float->bf16
    uint u = __float_as_uint(f);
    u += 0x7fff + ((u >> 16) & 1);
    return (ushort)(u >> 16);
}
__device__ inline float bf2f(ushort h) {
    return __uint_as_float(((uint)h) << 16);
}

// ---------------- K1: per-block coarse bucket histogram (LDS atomics on ints) ----------------

__global__ __launch_bounds__(256) void k_bucket_count(const int* __restrict__ dst,
                                                      int* __restrict__ bcnt) {
    __shared__ int h[NBUCK];
    int t = threadIdx.x;
    for (int b = t; b < NBUCK; b += 256) h[b] = 0;
    __syncthreads();
    int base = blockIdx.x * CHUNK;
    int end = base + CHUNK; if (end > N_EDGES) end = N_EDGES;
#pragma unroll
    for (int it = 0; it < 7; ++it) {
        int i = base + it * 256 + t;
        if (i < end) atomicAdd(&h[dst[i] >> 7], 1);
    }
    __syncthreads();
    for (int b = t; b < NBUCK; b += 256) bcnt[blockIdx.x * BSTRIDE + b] = h[b];
}

// ---------------- K2a: per-bucket column scan over 1024 blocks -> off, total ----------------

__global__ __launch_bounds__(256) void k_col_scan(const int* __restrict__ bcnt,
                                                  int* __restrict__ off,
                                                  int* __restrict__ total) {
    __shared__ int v[NBLK_B];
    __shared__ int ps[256];
    int t = threadIdx.x, b = blockIdx.x;
#pragma unroll
    for (int q = 0; q < NBLK_B / 256; ++q)
        v[q * 256 + t] = bcnt[(q * 256 + t) * BSTRIDE + b];
    __syncthreads();
    int l0 = v[t * 4], l1 = v[t * 4 + 1], l2 = v[t * 4 + 2], l3 = v[t * 4 + 3];
    ps[t] = l0 + l1 + l2 + l3;
    __syncthreads();
    for (int o = 1; o < 256; o <<= 1) {
        int u = (t >= o) ? ps[t - o] : 0;
        __syncthreads();
        ps[t] += u;
        __syncthreads();
    }
    int ex = (t > 0) ? ps[t - 1] : 0;
    off[(t * 4 + 0) * BSTRIDE + b] = ex; ex += l0;
    off[(t * 4 + 1) * BSTRIDE + b] = ex; ex += l1;
    off[(t * 4 + 2) * BSTRIDE + b] = ex; ex += l2;
    off[(t * 4 + 3) * BSTRIDE + b] = ex; ex += l3;
    if (t == 255) total[b] = ex;
}

// ---------------- K2b: scan bucket totals -> bucket_start ----------------

__global__ __launch_bounds__(256) void k_bucket_scan(const int* __restrict__ total,
                                                     int* __restrict__ bucket_start,
                                                     int* __restrict__ row_start) {
    __shared__ int ps[256];
    int t = threadIdx.x;
    int v[4];
    int base = t * 4;
#pragma unroll
    for (int q = 0; q < 4; ++q) v[q] = (base + q < NBUCK) ? total[base + q] : 0;
    ps[t] = v[0] + v[1] + v[2] + v[3];
    __syncthreads();
    for (int o = 1; o < 256; o <<= 1) {
        int u = (t >= o) ? ps[t - o] : 0;
        __syncthreads();
        ps[t] += u;
        __syncthreads();
    }
    int run = (t > 0) ? ps[t - 1] : 0;
#pragma unroll
    for (int q = 0; q < 4; ++q) {
        if (base + q <= NBUCK) bucket_start[base + q] = run;
        run += v[q];
    }
    if (t == 0) row_start[N_NODES] = N_EDGES;
}

// ------- K3 fat kernel: blocks [0,1024) scatter edges into buckets; rest do h1 = x@W1 -------

__global__ __launch_bounds__(256) void k_scatter_fat(const int* __restrict__ src,
                                                     const int* __restrict__ dst,
                                                     const int* __restrict__ bucket_start,
                                                     const int* __restrict__ off,
                                                     int* __restrict__ tmp,
                                                     const float* __restrict__ x,
                                                     const float* __restrict__ W1,
                                                     ushort* __restrict__ h1b) {
    __shared__ float smem[GROWS * IN_C];  // 8 KiB
    int t = threadIdx.x;
    if (blockIdx.x < NBLK_B) {
        // bucket scatter: write window per (block, bucket) is disjoint
        int* cur = (int*)smem;
        for (int b = t; b < NBUCK; b += 256)
            cur[b] = bucket_start[b] + off[blockIdx.x * BSTRIDE + b];
        __syncthreads();
        int base = blockIdx.x * CHUNK;
        int end = base + CHUNK; if (end > N_EDGES) end = N_EDGES;
#pragma unroll
        for (int it = 0; it < 7; ++it) {
            int i = base + it * 256 + t;
            if (i < end) {
                int s = src[i], d = dst[i];
                int b = d >> 7;
                int p = atomicAdd(&cur[b], 1);
                tmp[p] = (s << 7) | (d & 127);
            }
        }
    } else {
        // h1 = x @ W1, 16 rows/block; x tile in LDS, W1 streamed from L1/L2
        int rowbase = (blockIdx.x - NBLK_B) * GROWS;
#pragma unroll
        for (int q = 0; q < 8; ++q)
            smem[q * 256 + t] = x[rowbase * IN_C + q * 256 + t];
        __syncthreads();
        int wave = t >> 6, lane = t & 63;
        int rl0 = wave * 4;
        float a0 = 0.f, a1 = 0.f, a2 = 0.f, a3 = 0.f;
#pragma unroll 4
        for (int k = 0; k < IN_C; k += 4) {
            float4 x0 = *(const float4*)&smem[(rl0 + 0) * IN_C + k];
            float4 x1 = *(const float4*)&smem[(rl0 + 1) * IN_C + k];
            float4 x2 = *(const float4*)&smem[(rl0 + 2) * IN_C + k];
            float4 x3 = *(const float4*)&smem[(rl0 + 3) * IN_C + k];
            float w0 = W1[(k + 0) * HID_C + lane];
            float w1 = W1[(k + 1) * HID_C + lane];
            float w2 = W1[(k + 2) * HID_C + lane];
            float w3 = W1[(k + 3) * HID_C + lane];
            a0 += x0.x * w0 + x0.y * w1 + x0.z * w2 + x0.w * w3;
            a1 += x1.x * w0 + x1.y * w1 + x1.z * w2 + x1.w * w3;
            a2 += x2.x * w0 + x2.y * w1 + x2.z * w2 + x2.w * w3;
            a3 += x3.x * w0 + x3.y * w1 + x3.z * w2 + x3.w * w3;
        }
        int row = rowbase + rl0;
        h1b[(row + 0) * HID_C + lane] = f2bf(a0);
        h1b[(row + 1) * HID_C + lane] = f2bf(a1);
        h1b[(row + 2) * HID_C + lane] = f2bf(a2);
        h1b[(row + 3) * HID_C + lane] = f2bf(a3);
    }
}

// ------- K4: per-bucket CSR build (LDS hist + scan + cursors), emits row_start/dinv/eidx -------

__global__ __launch_bounds__(256) void k_csr_build(const int* __restrict__ bucket_start,
                                                   const int* __restrict__ tmp,
                                                   int* __restrict__ row_start,
                                                   int* __restrict__ eidx,
                                                   float* __restrict__ dinv) {
    __shared__ int h[128];
    __shared__ int cur[128];
    int b = blockIdx.x, t = threadIdx.x;
    int e0 = bucket_start[b], e1 = bucket_start[b + 1];
    if (t < 128) h[t] = 0;
    int pk[MAXPT];
#pragma unroll
    for (int k = 0; k < MAXPT; ++k) {
        int i = e0 + k * 256 + t;
        pk[k] = (i < e1) ? tmp[i] : -1;
    }
    __syncthreads();
#pragma unroll
    for (int k = 0; k < MAXPT; ++k)
        if (pk[k] >= 0) atomicAdd(&h[pk[k] & 127], 1);
    for (int i = e0 + MAXPT * 256 + t; i < e1; i += 256)  // safety tail
        atomicAdd(&h[tmp[i] & 127], 1);
    __syncthreads();
    int d0 = (t < 128) ? h[t] : 0;
    for (int o = 1; o < 128; o <<= 1) {
        int u = (t >= o && t < 128) ? h[t - o] : 0;
        __syncthreads();
        if (t < 128) h[t] += u;
        __syncthreads();
    }
    int g = b * 128 + t;
    if (t < 128 && g < N_NODES) {
        int ex = h[t] - d0;
        row_start[g] = e0 + ex;
        cur[t]       = e0 + ex;
        dinv[g] = rsqrtf((float)(d0 + 1));  // +1 self loop
    }
    __syncthreads();
#pragma unroll
    for (int k = 0; k < MAXPT; ++k)
        if (pk[k] >= 0) {
            int p = atomicAdd(&cur[pk[k] & 127], 1);
            eidx[p] = pk[k] >> 7;
        }
    for (int i = e0 + MAXPT * 256 + t; i < e1; i += 256) {
        int v = tmp[i];
        int p = atomicAdd(&cur[v & 127], 1);
        eidx[p] = v >> 7;
    }
}

// ------- K5: gather layer 1 + relu + FUSED gemm2 -> hs2 (bf16) -------
// 256 thr, 8 nodes/block, 32 lanes/node (lane owns a bf16x2 channel pair).
// a1 row kept in LDS tile; epilogue does 64x32 matmul with LDS-staged W2.

__global__ __launch_bounds__(256) void k_gather1f(const int* __restrict__ row_start,
                                                  const int* __restrict__ eidx,
                                                  const uint* __restrict__ h1u,
                                                  const float* __restrict__ dinv,
                                                  const float* __restrict__ b1,
                                                  const float* __restrict__ W2,
                                                  ushort* __restrict__ hs2b) {
    __shared__ float a1s[8][HID_C];       // 2 KiB
    __shared__ float W2s[HID_C * OUT_C];  // 8 KiB
    int t = threadIdx.x;
    for (int i = t; i < HID_C * OUT_C; i += 256) W2s[i] = W2[i];
    int sub = t & 31;
    int r = t >> 5;                        // 0..7
    int node = blockIdx.x * 8 + r;         // N_NODES divisible by 8

    float dn = dinv[node];
    int rs = row_start[node];
    int re = row_start[node + 1];
    uint su = h1u[node * 32 + sub];
    float accx = dn * __uint_as_float(su << 16);
    float accy = dn * __uint_as_float(su & 0xffff0000u);
    int j = rs;
    for (; j + 3 < re; j += 4) {
        int s0 = eidx[j], s1 = eidx[j + 1], s2 = eidx[j + 2], s3 = eidx[j + 3];
        float g0 = dinv[s0], g1 = dinv[s1], g2 = dinv[s2], g3 = dinv[s3];
        uint u0 = h1u[s0 * 32 + sub];
        uint u1 = h1u[s1 * 32 + sub];
        uint u2 = h1u[s2 * 32 + sub];
        uint u3 = h1u[s3 * 32 + sub];
        accx += g0 * __uint_as_float(u0 << 16) + g1 * __uint_as_float(u1 << 16)
              + g2 * __uint_as_float(u2 << 16) + g3 * __uint_as_float(u3 << 16);
        accy += g0 * __uint_as_float(u0 & 0xffff0000u) + g1 * __uint_as_float(u1 & 0xffff0000u)
              + g2 * __uint_as_float(u2 & 0xffff0000u) + g3 * __uint_as_float(u3 & 0xffff0000u);
    }
    for (; j < re; ++j) {
        int s = eidx[j];
        float g = dinv[s];
        uint u = h1u[s * 32 + sub];
        accx += g * __uint_as_float(u << 16);
        accy += g * __uint_as_float(u & 0xffff0000u);
    }
    float2 bb = *(const float2*)&b1[sub * 2];
    a1s[r][sub * 2 + 0] = fmaxf(dn * accx + bb.x, 0.f);
    a1s[r][sub * 2 + 1] = fmaxf(dn * accy + bb.y, 0.f);
    __syncthreads();

    // fused gemm2: thread (r, o=sub): hs2[node][o] = dn * sum_k a1s[r][k] * W2[k][o]
    float sum = 0.f;
#pragma unroll 8
    for (int k = 0; k < HID_C; ++k)
        sum += a1s[r][k] * W2s[k * OUT_C + sub];
    hs2b[node * OUT_C + sub] = f2bf(dn * sum);
}

// ------- K6: gather layer 2 (bf16 hs2) + epilogue -> out -------
// 256 thr, 8 nodes/block, 32 lanes/node (lane = out channel).

__global__ __launch_bounds__(256) void k_gather2(const int* __restrict__ row_start,
                                                 const int* __restrict__ eidx,
                                                 const ushort* __restrict__ hs2b,
                                                 const float* __restrict__ dinv,
                                                 const float* __restrict__ b2,
                                                 float* __restrict__ out) {
    int t = threadIdx.x;
    int sub = t & 31;
    int node = blockIdx.x * 8 + (t >> 5);  // N_NODES divisible by 8

    float dn = dinv[node];
    int rs = row_start[node];
    int re = row_start[node + 1];
    float acc = bf2f(hs2b[node * OUT_C + sub]);  // self loop
    int j = rs;
    for (; j + 3 < re; j += 4) {
        int s0 = eidx[j], s1 = eidx[j + 1], s2 = eidx[j + 2], s3 = eidx[j + 3];
        float v0 = bf2f(hs2b[s0 * OUT_C + sub]);
        float v1 = bf2f(hs2b[s1 * OUT_C + sub]);
        float v2 = bf2f(hs2b[s2 * OUT_C + sub]);
        float v3 = bf2f(hs2b[s3 * OUT_C + sub]);
        acc += v0 + v1 + v2 + v3;
    }
    for (; j < re; ++j) acc += bf2f(hs2b[eidx[j] * OUT_C + sub]);

    out[node * OUT_C + sub] = dn * acc + b2[sub];
}

extern "C" void kernel_launch(void* const* d_in, const int* in_sizes, int n_in,
                              void* d_out, int out_size, void* d_ws, size_t ws_size,
                              hipStream_t stream) {
    const float* x  = (const float*)d_in[0];
    const int* ei   = (const int*)d_in[1];   // [2, E]: src then dst
    const float* W1 = (const float*)d_in[2];
    const float* b1 = (const float*)d_in[3];
    const float* W2 = (const float*)d_in[4];
    const float* b2 = (const float*)d_in[5];
    float* out = (float*)d_out;

    const int* src = ei;
    const int* dst = ei + N_EDGES;

    // workspace layout (bytes), total ~41.2 MB
    char* ws = (char*)d_ws;
    int*    row_start    = (int*)(ws + 0);            //   400,128 (N+1 ints)
    float*  dinv         = (float*)(ws + 400128);     //   400,128
    int*    bucket_start = (int*)(ws + 800256);       //     4,096
    int*    total        = (int*)(ws + 804352);       //     4,096
    int*    bcnt         = (int*)(ws + 808448);       // 4,194,304
    int*    off          = (int*)(ws + 5002752);      // 4,194,304
    int*    eidx         = (int*)(ws + 9197056);      // 6,400,000
    int*    tmp          = (int*)(ws + 15597056);     // 6,400,000
    ushort* h1b          = (ushort*)(ws + 21997056);  // 12,800,000 (bf16)
    ushort* hs2b         = (ushort*)(ws + 34797056);  //  6,400,000 (bf16)

    k_bucket_count<<<NBLK_B, 256, 0, stream>>>(dst, bcnt);
    k_col_scan<<<NBUCK, 256, 0, stream>>>(bcnt, off, total);
    k_bucket_scan<<<1, 256, 0, stream>>>(total, bucket_start, row_start);

    k_scatter_fat<<<NBLK_B + GEMM_BLKS, 256, 0, stream>>>(src, dst, bucket_start, off,
                                                          tmp, x, W1, h1b);
    k_csr_build<<<NBUCK, 256, 0, stream>>>(bucket_start, tmp, row_start, eidx, dinv);

    k_gather1f<<<N_NODES / 8, 256, 0, stream>>>(row_start, eidx, (const uint*)h1b,
                                                dinv, b1, W2, hs2b);
    k_gather2<<<N_NODES / 8, 256, 0, stream>>>(row_start, eidx, hs2b, dinv, b2, out);
}

// Round 9
// 162.553 us; speedup vs baseline: 6.8381x; 1.1900x over previous
//
#include <hip/hip_runtime.h>

#define N_NODES 100000
#define N_EDGES 1600000
#define IN_C 128
#define HID_C 64
#define OUT_C 32

#define NBUCK 782        // ceil(100000 / 128) buckets of 128 nodes
#define NBLK_B 256       // edge-chunk blocks for bucket count/scatter
#define CHUNK 6250       // N_EDGES / NBLK_B (exact)
#define BSTRIDE 1024     // padded stride for bcnt/off tables
#define MAXPT 12         // per-thread reg capacity in CSR build (3072/bucket)

#define GROWS 16         // rows per GEMM block
#define GEMM_BLKS 6250   // N_NODES / GROWS (exact)

typedef unsigned int uint;
typedef unsigned short ushort;

__device__ inline ushort f2bf(float f) {   // RNE float->bf16
    uint u = __float_as_uint(f);
    u += 0x7fff + ((u >> 16) & 1);
    return (ushort)(u >> 16);
}
__device__ inline float bf2f(ushort h) {
    return __uint_as_float(((uint)h) << 16);
}

// ---------------- K1: per-block coarse bucket histogram (LDS atomics on ints) ----------------

__global__ __launch_bounds__(256) void k_bucket_count(const int* __restrict__ dst,
                                                      int* __restrict__ bcnt) {
    __shared__ int h[NBUCK];
    int t = threadIdx.x;
    for (int b = t; b < NBUCK; b += 256) h[b] = 0;
    __syncthreads();
    int base = blockIdx.x * CHUNK;
    int end = base + CHUNK;
    for (int i = base + t; i < end; i += 256) atomicAdd(&h[dst[i] >> 7], 1);
    __syncthreads();
    for (int b = t; b < NBUCK; b += 256) bcnt[blockIdx.x * BSTRIDE + b] = h[b];
}

// ---------------- K2a: per-bucket column scan over 256 blocks -> off, total ----------------

__global__ __launch_bounds__(256) void k_col_scan(const int* __restrict__ bcnt,
                                                  int* __restrict__ off,
                                                  int* __restrict__ total) {
    __shared__ int ps[256];
    int t = threadIdx.x, b = blockIdx.x;
    int l = bcnt[t * BSTRIDE + b];
    ps[t] = l;
    __syncthreads();
    for (int o = 1; o < 256; o <<= 1) {
        int u = (t >= o) ? ps[t - o] : 0;
        __syncthreads();
        ps[t] += u;
        __syncthreads();
    }
    off[t * BSTRIDE + b] = ps[t] - l;  // exclusive prefix
    if (t == 255) total[b] = ps[255];
}

// ---------------- K2b: scan bucket totals -> bucket_start ----------------

__global__ __launch_bounds__(256) void k_bucket_scan(const int* __restrict__ total,
                                                     int* __restrict__ bucket_start,
                                                     int* __restrict__ row_start) {
    __shared__ int ps[256];
    int t = threadIdx.x;
    int v[4];
    int base = t * 4;
#pragma unroll
    for (int q = 0; q < 4; ++q) v[q] = (base + q < NBUCK) ? total[base + q] : 0;
    ps[t] = v[0] + v[1] + v[2] + v[3];
    __syncthreads();
    for (int o = 1; o < 256; o <<= 1) {
        int u = (t >= o) ? ps[t - o] : 0;
        __syncthreads();
        ps[t] += u;
        __syncthreads();
    }
    int run = (t > 0) ? ps[t - 1] : 0;
#pragma unroll
    for (int q = 0; q < 4; ++q) {
        if (base + q <= NBUCK) bucket_start[base + q] = run;
        run += v[q];
    }
    if (t == 0) row_start[N_NODES] = N_EDGES;
}

// ------- K3 fat kernel: blocks [0,256) scatter edges into buckets; rest do h1 = x@W1 -------

__global__ __launch_bounds__(256) void k_scatter_fat(const int* __restrict__ src,
                                                     const int* __restrict__ dst,
                                                     const int* __restrict__ bucket_start,
                                                     const int* __restrict__ off,
                                                     int* __restrict__ tmp,
                                                     const float* __restrict__ x,
                                                     const float* __restrict__ W1,
                                                     ushort* __restrict__ h1b) {
    __shared__ float smem[GROWS * IN_C];  // 8 KiB
    int t = threadIdx.x;
    if (blockIdx.x < NBLK_B) {
        // bucket scatter: write window per (block, bucket) is disjoint
        int* cur = (int*)smem;
        for (int b = t; b < NBUCK; b += 256)
            cur[b] = bucket_start[b] + off[blockIdx.x * BSTRIDE + b];
        __syncthreads();
        int base = blockIdx.x * CHUNK;
        int end = base + CHUNK;
        for (int i = base + t; i < end; i += 256) {
            int s = src[i], d = dst[i];
            int b = d >> 7;
            int p = atomicAdd(&cur[b], 1);
            tmp[p] = (s << 7) | (d & 127);
        }
    } else {
        // h1 = x @ W1, 16 rows/block; x tile in LDS (wave-uniform broadcast reads),
        // W1 streamed from L1 (32KB, hot). VGPR ~32 -> 8 waves/SIMD.
        int rowbase = (blockIdx.x - NBLK_B) * GROWS;
#pragma unroll
        for (int q = 0; q < 8; ++q)
            smem[q * 256 + t] = x[rowbase * IN_C + q * 256 + t];
        __syncthreads();
        int wave = t >> 6, lane = t & 63;
        int rl0 = wave * 4;
        float a0 = 0.f, a1 = 0.f, a2 = 0.f, a3 = 0.f;
#pragma unroll 8
        for (int k = 0; k < IN_C; ++k) {
            float w = W1[k * HID_C + lane];
            a0 += smem[(rl0 + 0) * IN_C + k] * w;
            a1 += smem[(rl0 + 1) * IN_C + k] * w;
            a2 += smem[(rl0 + 2) * IN_C + k] * w;
            a3 += smem[(rl0 + 3) * IN_C + k] * w;
        }
        int row = rowbase + rl0;
        h1b[(row + 0) * HID_C + lane] = f2bf(a0);
        h1b[(row + 1) * HID_C + lane] = f2bf(a1);
        h1b[(row + 2) * HID_C + lane] = f2bf(a2);
        h1b[(row + 3) * HID_C + lane] = f2bf(a3);
    }
}

// ------- K4: per-bucket CSR build (LDS hist + scan + cursors), emits row_start/dinv/eidx -------

__global__ __launch_bounds__(256) void k_csr_build(const int* __restrict__ bucket_start,
                                                   const int* __restrict__ tmp,
                                                   int* __restrict__ row_start,
                                                   int* __restrict__ eidx,
                                                   float* __restrict__ dinv) {
    __shared__ int h[128];
    __shared__ int cur[128];
    int b = blockIdx.x, t = threadIdx.x;
    int e0 = bucket_start[b], e1 = bucket_start[b + 1];
    if (t < 128) h[t] = 0;
    int pk[MAXPT];
#pragma unroll
    for (int k = 0; k < MAXPT; ++k) {
        int i = e0 + k * 256 + t;
        pk[k] = (i < e1) ? tmp[i] : -1;
    }
    __syncthreads();
#pragma unroll
    for (int k = 0; k < MAXPT; ++k)
        if (pk[k] >= 0) atomicAdd(&h[pk[k] & 127], 1);
    for (int i = e0 + MAXPT * 256 + t; i < e1; i += 256)  // safety tail
        atomicAdd(&h[tmp[i] & 127], 1);
    __syncthreads();
    int d0 = (t < 128) ? h[t] : 0;
    for (int o = 1; o < 128; o <<= 1) {
        int u = (t >= o && t < 128) ? h[t - o] : 0;
        __syncthreads();
        if (t < 128) h[t] += u;
        __syncthreads();
    }
    int g = b * 128 + t;
    if (t < 128 && g < N_NODES) {
        int ex = h[t] - d0;
        row_start[g] = e0 + ex;
        cur[t]       = e0 + ex;
        dinv[g] = rsqrtf((float)(d0 + 1));  // +1 self loop
    }
    __syncthreads();
#pragma unroll
    for (int k = 0; k < MAXPT; ++k)
        if (pk[k] >= 0) {
            int p = atomicAdd(&cur[pk[k] & 127], 1);
            eidx[p] = pk[k] >> 7;
        }
    for (int i = e0 + MAXPT * 256 + t; i < e1; i += 256) {
        int v = tmp[i];
        int p = atomicAdd(&cur[v & 127], 1);
        eidx[p] = v >> 7;
    }
}

// ------- K5: gather layer 1 + relu + FUSED gemm2 -> hs2 (bf16) -------
// 256 thr; 4 node-groups of 8 per block (W2 staged once); 32 lanes/node.

__global__ __launch_bounds__(256) void k_gather1f(const int* __restrict__ row_start,
                                                  const int* __restrict__ eidx,
                                                  const uint* __restrict__ h1u,
                                                  const float* __restrict__ dinv,
                                                  const float* __restrict__ b1,
                                                  const float* __restrict__ W2,
                                                  ushort* __restrict__ hs2b) {
    __shared__ float a1s[8][HID_C];       // 2 KiB
    __shared__ float W2s[HID_C * OUT_C];  // 8 KiB
    int t = threadIdx.x;
    for (int i = t; i < HID_C * OUT_C; i += 256) W2s[i] = W2[i];
    int sub = t & 31;
    int r = t >> 5;  // 0..7
    float2 bb = *(const float2*)&b1[sub * 2];

    for (int g = 0; g < 4; ++g) {
        int node = (blockIdx.x * 4 + g) * 8 + r;  // N_NODES = 3125*4*8 exact
        float dn = dinv[node];
        int rs = row_start[node];
        int re = row_start[node + 1];
        uint su = h1u[node * 32 + sub];
        float accx = dn * __uint_as_float(su << 16);
        float accy = dn * __uint_as_float(su & 0xffff0000u);
        int j = rs;
        for (; j + 7 < re; j += 8) {
            int s0 = eidx[j],     s1 = eidx[j + 1], s2 = eidx[j + 2], s3 = eidx[j + 3];
            int s4 = eidx[j + 4], s5 = eidx[j + 5], s6 = eidx[j + 6], s7 = eidx[j + 7];
            float g0 = dinv[s0], g1 = dinv[s1], g2 = dinv[s2], g3 = dinv[s3];
            float g4 = dinv[s4], g5 = dinv[s5], g6 = dinv[s6], g7 = dinv[s7];
            uint u0 = h1u[s0 * 32 + sub], u1 = h1u[s1 * 32 + sub];
            uint u2 = h1u[s2 * 32 + sub], u3 = h1u[s3 * 32 + sub];
            uint u4 = h1u[s4 * 32 + sub], u5 = h1u[s5 * 32 + sub];
            uint u6 = h1u[s6 * 32 + sub], u7 = h1u[s7 * 32 + sub];
            accx += g0 * __uint_as_float(u0 << 16) + g1 * __uint_as_float(u1 << 16)
                  + g2 * __uint_as_float(u2 << 16) + g3 * __uint_as_float(u3 << 16)
                  + g4 * __uint_as_float(u4 << 16) + g5 * __uint_as_float(u5 << 16)
                  + g6 * __uint_as_float(u6 << 16) + g7 * __uint_as_float(u7 << 16);
            accy += g0 * __uint_as_float(u0 & 0xffff0000u) + g1 * __uint_as_float(u1 & 0xffff0000u)
                  + g2 * __uint_as_float(u2 & 0xffff0000u) + g3 * __uint_as_float(u3 & 0xffff0000u)
                  + g4 * __uint_as_float(u4 & 0xffff0000u) + g5 * __uint_as_float(u5 & 0xffff0000u)
                  + g6 * __uint_as_float(u6 & 0xffff0000u) + g7 * __uint_as_float(u7 & 0xffff0000u);
        }
        for (; j + 3 < re; j += 4) {
            int s0 = eidx[j], s1 = eidx[j + 1], s2 = eidx[j + 2], s3 = eidx[j + 3];
            float g0 = dinv[s0], g1 = dinv[s1], g2 = dinv[s2], g3 = dinv[s3];
            uint u0 = h1u[s0 * 32 + sub], u1 = h1u[s1 * 32 + sub];
            uint u2 = h1u[s2 * 32 + sub], u3 = h1u[s3 * 32 + sub];
            accx += g0 * __uint_as_float(u0 << 16) + g1 * __uint_as_float(u1 << 16)
                  + g2 * __uint_as_float(u2 << 16) + g3 * __uint_as_float(u3 << 16);
            accy += g0 * __uint_as_float(u0 & 0xffff0000u) + g1 * __uint_as_float(u1 & 0xffff0000u)
                  + g2 * __uint_as_float(u2 & 0xffff0000u) + g3 * __uint_as_float(u3 & 0xffff0000u);
        }
        for (; j < re; ++j) {
            int s = eidx[j];
            float gg = dinv[s];
            uint u = h1u[s * 32 + sub];
            accx += gg * __uint_as_float(u << 16);
            accy += gg * __uint_as_float(u & 0xffff0000u);
        }
        __syncthreads();  // a1s free (W2 staged / previous gemm2 done)
        a1s[r][sub * 2 + 0] = fmaxf(dn * accx + bb.x, 0.f);
        a1s[r][sub * 2 + 1] = fmaxf(dn * accy + bb.y, 0.f);
        __syncthreads();

        // fused gemm2: thread (r, o=sub): hs2[node][o] = dn * sum_k a1s[r][k] * W2[k][o]
        float sum = 0.f;
#pragma unroll 8
        for (int k = 0; k < HID_C; ++k)
            sum += a1s[r][k] * W2s[k * OUT_C + sub];
        hs2b[node * OUT_C + sub] = f2bf(dn * sum);
    }
}

// ------- K6: gather layer 2 (bf16 hs2) + epilogue -> out -------
// 256 thr, 8 nodes/block, 32 lanes/node (lane = out channel).

__global__ __launch_bounds__(256) void k_gather2(const int* __restrict__ row_start,
                                                 const int* __restrict__ eidx,
                                                 const ushort* __restrict__ hs2b,
                                                 const float* __restrict__ dinv,
                                                 const float* __restrict__ b2,
                                                 float* __restrict__ out) {
    int t = threadIdx.x;
    int sub = t & 31;
    int node = blockIdx.x * 8 + (t >> 5);  // N_NODES divisible by 8

    float dn = dinv[node];
    int rs = row_start[node];
    int re = row_start[node + 1];
    float acc = bf2f(hs2b[node * OUT_C + sub]);  // self loop
    int j = rs;
    for (; j + 7 < re; j += 8) {
        int s0 = eidx[j],     s1 = eidx[j + 1], s2 = eidx[j + 2], s3 = eidx[j + 3];
        int s4 = eidx[j + 4], s5 = eidx[j + 5], s6 = eidx[j + 6], s7 = eidx[j + 7];
        float v0 = bf2f(hs2b[s0 * OUT_C + sub]);
        float v1 = bf2f(hs2b[s1 * OUT_C + sub]);
        float v2 = bf2f(hs2b[s2 * OUT_C + sub]);
        float v3 = bf2f(hs2b[s3 * OUT_C + sub]);
        float v4 = bf2f(hs2b[s4 * OUT_C + sub]);
        float v5 = bf2f(hs2b[s5 * OUT_C + sub]);
        float v6 = bf2f(hs2b[s6 * OUT_C + sub]);
        float v7 = bf2f(hs2b[s7 * OUT_C + sub]);
        acc += ((v0 + v1) + (v2 + v3)) + ((v4 + v5) + (v6 + v7));
    }
    for (; j + 3 < re; j += 4) {
        int s0 = eidx[j], s1 = eidx[j + 1], s2 = eidx[j + 2], s3 = eidx[j + 3];
        float v0 = bf2f(hs2b[s0 * OUT_C + sub]);
        float v1 = bf2f(hs2b[s1 * OUT_C + sub]);
        float v2 = bf2f(hs2b[s2 * OUT_C + sub]);
        float v3 = bf2f(hs2b[s3 * OUT_C + sub]);
        acc += (v0 + v1) + (v2 + v3);
    }
    for (; j < re; ++j) acc += bf2f(hs2b[eidx[j] * OUT_C + sub]);

    out[node * OUT_C + sub] = dn * acc + b2[sub];
}

extern "C" void kernel_launch(void* const* d_in, const int* in_sizes, int n_in,
                              void* d_out, int out_size, void* d_ws, size_t ws_size,
                              hipStream_t stream) {
    const float* x  = (const float*)d_in[0];
    const int* ei   = (const int*)d_in[1];   // [2, E]: src then dst
    const float* W1 = (const float*)d_in[2];
    const float* b1 = (const float*)d_in[3];
    const float* W2 = (const float*)d_in[4];
    const float* b2 = (const float*)d_in[5];
    float* out = (float*)d_out;

    const int* src = ei;
    const int* dst = ei + N_EDGES;

    // workspace layout (bytes), total ~34.9 MB
    char* ws = (char*)d_ws;
    int*    row_start    = (int*)(ws + 0);            //   400,128 (N+1 ints)
    float*  dinv         = (float*)(ws + 400128);     //   400,128
    int*    bucket_start = (int*)(ws + 800256);       //     4,096
    int*    total        = (int*)(ws + 804352);       //     4,096
    int*    bcnt         = (int*)(ws + 808448);       // 1,048,576
    int*    off          = (int*)(ws + 1857024);      // 1,048,576
    int*    eidx         = (int*)(ws + 2905600);      // 6,400,000
    int*    tmp          = (int*)(ws + 9305600);      // 6,400,000
    ushort* h1b          = (ushort*)(ws + 15705600);  // 12,800,000 (bf16)
    ushort* hs2b         = (ushort*)(ws + 28505600);  //  6,400,000 (bf16)

    k_bucket_count<<<NBLK_B, 256, 0, stream>>>(dst, bcnt);
    k_col_scan<<<NBUCK, 256, 0, stream>>>(bcnt, off, total);
    k_bucket_scan<<<1, 256, 0, stream>>>(total, bucket_start, row_start);

    k_scatter_fat<<<NBLK_B + GEMM_BLKS, 256, 0, stream>>>(src, dst, bucket_start, off,
                                                          tmp, x, W1, h1b);
    k_csr_build<<<NBUCK, 256, 0, stream>>>(bucket_start, tmp, row_start, eidx, dinv);

    k_gather1f<<<N_NODES / 32, 256, 0, stream>>>(row_start, eidx, (const uint*)h1b,
                                                 dinv, b1, W2, hs2b);
    k_gather2<<<N_NODES / 8, 256, 0, stream>>>(row_start, eidx, hs2b, dinv, b2, out);
}

// Round 10
// 148.187 us; speedup vs baseline: 7.5010x; 1.0969x over previous
//
#include <hip/hip_runtime.h>

#define N_NODES 100000
#define N_EDGES 1600000
#define IN_C 128
#define HID_C 64
#define OUT_C 32

#define NBUCK 782        // ceil(100000 / 128) buckets of 128 nodes
#define NBLK_B 256       // edge-chunk blocks for bucket count/scatter
#define CHUNK 6250       // N_EDGES / NBLK_B (exact)
#define BSTRIDE 1024     // padded stride for bcnt/off tables
#define MAXPT 12         // per-thread reg capacity in CSR build (3072/bucket)

#define MF_BLKS 1563     // ceil(N_NODES / 64) MFMA-GEMM blocks (64 rows each)

typedef unsigned int uint;
typedef unsigned short ushort;
typedef __attribute__((ext_vector_type(8))) short bf16x8;
typedef __attribute__((ext_vector_type(4))) float f32x4;

__device__ inline ushort f2bf(float f) {   // RNE float->bf16
    uint u = __float_as_uint(f);
    u += 0x7fff + ((u >> 16) & 1);
    return (ushort)(u >> 16);
}
__device__ inline float bf2f(ushort h) {
    return __uint_as_float(((uint)h) << 16);
}

// ---------------- K1: per-block coarse bucket histogram (LDS atomics on ints) ----------------

__global__ __launch_bounds__(256) void k_bucket_count(const int* __restrict__ dst,
                                                      int* __restrict__ bcnt) {
    __shared__ int h[NBUCK];
    int t = threadIdx.x;
    for (int b = t; b < NBUCK; b += 256) h[b] = 0;
    __syncthreads();
    int base = blockIdx.x * CHUNK;
    int end = base + CHUNK;
    for (int i = base + t; i < end; i += 256) atomicAdd(&h[dst[i] >> 7], 1);
    __syncthreads();
    for (int b = t; b < NBUCK; b += 256) bcnt[blockIdx.x * BSTRIDE + b] = h[b];
}

// ---------------- K2a: per-bucket column scan over 256 blocks -> off, total ----------------

__global__ __launch_bounds__(256) void k_col_scan(const int* __restrict__ bcnt,
                                                  int* __restrict__ off,
                                                  int* __restrict__ total) {
    __shared__ int ps[256];
    int t = threadIdx.x, b = blockIdx.x;
    int l = bcnt[t * BSTRIDE + b];
    ps[t] = l;
    __syncthreads();
    for (int o = 1; o < 256; o <<= 1) {
        int u = (t >= o) ? ps[t - o] : 0;
        __syncthreads();
        ps[t] += u;
        __syncthreads();
    }
    off[t * BSTRIDE + b] = ps[t] - l;  // exclusive prefix
    if (t == 255) total[b] = ps[255];
}

// ---------------- K2b: scan bucket totals -> bucket_start ----------------

__global__ __launch_bounds__(256) void k_bucket_scan(const int* __restrict__ total,
                                                     int* __restrict__ bucket_start,
                                                     int* __restrict__ row_start) {
    __shared__ int ps[256];
    int t = threadIdx.x;
    int v[4];
    int base = t * 4;
#pragma unroll
    for (int q = 0; q < 4; ++q) v[q] = (base + q < NBUCK) ? total[base + q] : 0;
    ps[t] = v[0] + v[1] + v[2] + v[3];
    __syncthreads();
    for (int o = 1; o < 256; o <<= 1) {
        int u = (t >= o) ? ps[t - o] : 0;
        __syncthreads();
        ps[t] += u;
        __syncthreads();
    }
    int run = (t > 0) ? ps[t - 1] : 0;
#pragma unroll
    for (int q = 0; q < 4; ++q) {
        if (base + q <= NBUCK) bucket_start[base + q] = run;
        run += v[q];
    }
    if (t == 0) row_start[N_NODES] = N_EDGES;
}

// ------- K3 fat kernel: blocks [0,256) scatter edges into buckets; rest do h1 = x@W1 (MFMA) -------

__global__ __launch_bounds__(256) void k_scatter_fat(const int* __restrict__ src,
                                                     const int* __restrict__ dst,
                                                     const int* __restrict__ bucket_start,
                                                     const int* __restrict__ off,
                                                     int* __restrict__ tmp,
                                                     const float* __restrict__ x,
                                                     const float* __restrict__ W1,
                                                     ushort* __restrict__ h1b) {
    __shared__ uint smu[4096];  // 16 KiB: scatter cursor table / W1 bf16 fragments
    int t = threadIdx.x;
    if (blockIdx.x < NBLK_B) {
        // bucket scatter: write window per (block, bucket) is disjoint
        int* cur = (int*)smu;
        for (int b = t; b < NBUCK; b += 256)
            cur[b] = bucket_start[b] + off[blockIdx.x * BSTRIDE + b];
        __syncthreads();
        int base = blockIdx.x * CHUNK;
        int end = base + CHUNK;
        for (int i = base + t; i < end; i += 256) {
            int s = src[i], d = dst[i];
            int b = d >> 7;
            int p = atomicAdd(&cur[b], 1);
            tmp[p] = (s << 7) | (d & 127);
        }
    } else {
        // h1 = x @ W1 via mfma_f32_16x16x32_bf16. 64 rows/block, wave w -> rows w*16..w*16+15.
        // Fragment layouts: A row=lane&15, k=(lane>>4)*8+j; B k likewise, col=lane&15;
        // D col=lane&15, row=(lane>>4)*4+reg (guide-verified).
        int g = blockIdx.x - NBLK_B;
        // build W1 bf16 B-fragments in LDS: smu[((kt*4+ct)*64 + lane)*4 + dw]
#pragma unroll
        for (int i = 0; i < 16; ++i) {
            int lin = i * 256 + t;           // 0..4095
            int frag = lin >> 8;             // 0..15 = kt*4+ct
            int lane_ = (lin >> 2) & 63;
            int dw = lin & 3;
            int k = ((frag >> 2) << 5) + ((lane_ >> 4) << 3) + dw * 2;
            int c = ((frag & 3) << 4) + (lane_ & 15);
            smu[lin] = ((uint)f2bf(W1[(k + 1) * HID_C + c]) << 16) | f2bf(W1[k * HID_C + c]);
        }
        __syncthreads();
        int wave = t >> 6, lane = t & 63;
        int row0 = g * 64 + wave * 16;
        bf16x8 bfr[4][4];
#pragma unroll
        for (int kt = 0; kt < 4; ++kt)
#pragma unroll
            for (int ct = 0; ct < 4; ++ct)
                bfr[kt][ct] = *(bf16x8*)&smu[((kt * 4 + ct) * 64 + lane) * 4];
        int arow = row0 + (lane & 15);
        if (arow > N_NODES - 1) arow = N_NODES - 1;  // tail block: clamp loads, guard stores
        int kbase = (lane >> 4) * 8;
        f32x4 acc0 = {0.f, 0.f, 0.f, 0.f}, acc1 = {0.f, 0.f, 0.f, 0.f};
        f32x4 acc2 = {0.f, 0.f, 0.f, 0.f}, acc3 = {0.f, 0.f, 0.f, 0.f};
#pragma unroll
        for (int kt = 0; kt < 4; ++kt) {
            const float* xp = &x[arow * IN_C + kt * 32 + kbase];
            float4 u0 = *(const float4*)xp;
            float4 u1 = *(const float4*)(xp + 4);
            union { uint u[4]; bf16x8 v; } A;
            A.u[0] = ((uint)f2bf(u0.y) << 16) | f2bf(u0.x);
            A.u[1] = ((uint)f2bf(u0.w) << 16) | f2bf(u0.z);
            A.u[2] = ((uint)f2bf(u1.y) << 16) | f2bf(u1.x);
            A.u[3] = ((uint)f2bf(u1.w) << 16) | f2bf(u1.z);
            acc0 = __builtin_amdgcn_mfma_f32_16x16x32_bf16(A.v, bfr[kt][0], acc0, 0, 0, 0);
            acc1 = __builtin_amdgcn_mfma_f32_16x16x32_bf16(A.v, bfr[kt][1], acc1, 0, 0, 0);
            acc2 = __builtin_amdgcn_mfma_f32_16x16x32_bf16(A.v, bfr[kt][2], acc2, 0, 0, 0);
            acc3 = __builtin_amdgcn_mfma_f32_16x16x32_bf16(A.v, bfr[kt][3], acc3, 0, 0, 0);
        }
        int rbase = row0 + ((lane >> 4) << 2);
        int cb = lane & 15;
#pragma unroll
        for (int r = 0; r < 4; ++r) {
            int row = rbase + r;
            if (row < N_NODES) {
                h1b[row * HID_C + cb]      = f2bf(acc0[r]);
                h1b[row * HID_C + 16 + cb] = f2bf(acc1[r]);
                h1b[row * HID_C + 32 + cb] = f2bf(acc2[r]);
                h1b[row * HID_C + 48 + cb] = f2bf(acc3[r]);
            }
        }
    }
}

// ------- K4: per-bucket CSR build + h1 prescale (h~ = bf16(dinv*h1)) -------

__global__ __launch_bounds__(256) void k_csr_build(const int* __restrict__ bucket_start,
                                                   const int* __restrict__ tmp,
                                                   int* __restrict__ row_start,
                                                   int* __restrict__ eidx,
                                                   float* __restrict__ dinv,
                                                   uint* __restrict__ h1u) {
    __shared__ int h[128];
    __shared__ int cur[128];
    __shared__ float dl[128];
    int b = blockIdx.x, t = threadIdx.x;
    int e0 = bucket_start[b], e1 = bucket_start[b + 1];
    if (t < 128) h[t] = 0;
    int pk[MAXPT];
#pragma unroll
    for (int k = 0; k < MAXPT; ++k) {
        int i = e0 + k * 256 + t;
        pk[k] = (i < e1) ? tmp[i] : -1;
    }
    __syncthreads();
#pragma unroll
    for (int k = 0; k < MAXPT; ++k)
        if (pk[k] >= 0) atomicAdd(&h[pk[k] & 127], 1);
    for (int i = e0 + MAXPT * 256 + t; i < e1; i += 256)  // safety tail
        atomicAdd(&h[tmp[i] & 127], 1);
    __syncthreads();
    int d0 = (t < 128) ? h[t] : 0;
    for (int o = 1; o < 128; o <<= 1) {
        int u = (t >= o && t < 128) ? h[t - o] : 0;
        __syncthreads();
        if (t < 128) h[t] += u;
        __syncthreads();
    }
    int g = b * 128 + t;
    if (t < 128 && g < N_NODES) {
        int ex = h[t] - d0;
        row_start[g] = e0 + ex;
        cur[t]       = e0 + ex;
        float dv = rsqrtf((float)(d0 + 1));  // +1 self loop
        dinv[g] = dv;
        dl[t] = dv;
    }
    __syncthreads();
#pragma unroll
    for (int k = 0; k < MAXPT; ++k)
        if (pk[k] >= 0) {
            int p = atomicAdd(&cur[pk[k] & 127], 1);
            eidx[p] = pk[k] >> 7;
        }
    for (int i = e0 + MAXPT * 256 + t; i < e1; i += 256) {
        int v = tmp[i];
        int p = atomicAdd(&cur[v & 127], 1);
        eidx[p] = v >> 7;
    }
    // prescale this bucket's h1 rows by dinv (bf16x2 per uint)
    int bu = b * 128 * (HID_C / 2);
    for (int i = t; i < 128 * (HID_C / 2); i += 256) {
        int rl = i >> 5;
        int gg = b * 128 + rl;
        if (gg < N_NODES) {
            float dv = dl[rl];
            uint v = h1u[bu + i];
            float lo = __uint_as_float(v << 16) * dv;
            float hi = __uint_as_float(v & 0xffff0000u) * dv;
            h1u[bu + i] = ((uint)f2bf(hi) << 16) | f2bf(lo);
        }
    }
}

// ------- K5: gather layer 1 (prescaled h~) + relu + FUSED gemm2 -> hs2 (bf16) -------
// 256 thr; 4 node-groups of 8 per block (W2 staged once); 32 lanes/node.

__global__ __launch_bounds__(256) void k_gather1f(const int* __restrict__ row_start,
                                                  const int* __restrict__ eidx,
                                                  const uint* __restrict__ h1u,
                                                  const float* __restrict__ dinv,
                                                  const float* __restrict__ b1,
                                                  const float* __restrict__ W2,
                                                  ushort* __restrict__ hs2b) {
    __shared__ float a1s[8][HID_C];       // 2 KiB
    __shared__ float W2s[HID_C * OUT_C];  // 8 KiB
    int t = threadIdx.x;
    for (int i = t; i < HID_C * OUT_C; i += 256) W2s[i] = W2[i];
    int sub = t & 31;
    int r = t >> 5;  // 0..7
    float2 bb = *(const float2*)&b1[sub * 2];

    for (int g = 0; g < 4; ++g) {
        int node = (blockIdx.x * 4 + g) * 8 + r;  // N_NODES = 3125*4*8 exact
        float dn = dinv[node];
        int rs = row_start[node];
        int re = row_start[node + 1];
        uint su = h1u[node * 32 + sub];           // self term: already dinv-scaled
        float accx = __uint_as_float(su << 16);
        float accy = __uint_as_float(su & 0xffff0000u);
        int j = rs;
        for (; j + 7 < re; j += 8) {
            int s0 = eidx[j],     s1 = eidx[j + 1], s2 = eidx[j + 2], s3 = eidx[j + 3];
            int s4 = eidx[j + 4], s5 = eidx[j + 5], s6 = eidx[j + 6], s7 = eidx[j + 7];
            uint u0 = h1u[s0 * 32 + sub], u1 = h1u[s1 * 32 + sub];
            uint u2 = h1u[s2 * 32 + sub], u3 = h1u[s3 * 32 + sub];
            uint u4 = h1u[s4 * 32 + sub], u5 = h1u[s5 * 32 + sub];
            uint u6 = h1u[s6 * 32 + sub], u7 = h1u[s7 * 32 + sub];
            accx += (__uint_as_float(u0 << 16) + __uint_as_float(u1 << 16))
                  + (__uint_as_float(u2 << 16) + __uint_as_float(u3 << 16))
                  + (__uint_as_float(u4 << 16) + __uint_as_float(u5 << 16))
                  + (__uint_as_float(u6 << 16) + __uint_as_float(u7 << 16));
            accy += (__uint_as_float(u0 & 0xffff0000u) + __uint_as_float(u1 & 0xffff0000u))
                  + (__uint_as_float(u2 & 0xffff0000u) + __uint_as_float(u3 & 0xffff0000u))
                  + (__uint_as_float(u4 & 0xffff0000u) + __uint_as_float(u5 & 0xffff0000u))
                  + (__uint_as_float(u6 & 0xffff0000u) + __uint_as_float(u7 & 0xffff0000u));
        }
        for (; j + 3 < re; j += 4) {
            int s0 = eidx[j], s1 = eidx[j + 1], s2 = eidx[j + 2], s3 = eidx[j + 3];
            uint u0 = h1u[s0 * 32 + sub], u1 = h1u[s1 * 32 + sub];
            uint u2 = h1u[s2 * 32 + sub], u3 = h1u[s3 * 32 + sub];
            accx += (__uint_as_float(u0 << 16) + __uint_as_float(u1 << 16))
                  + (__uint_as_float(u2 << 16) + __uint_as_float(u3 << 16));
            accy += (__uint_as_float(u0 & 0xffff0000u) + __uint_as_float(u1 & 0xffff0000u))
                  + (__uint_as_float(u2 & 0xffff0000u) + __uint_as_float(u3 & 0xffff0000u));
        }
        for (; j < re; ++j) {
            uint u = h1u[eidx[j] * 32 + sub];
            accx += __uint_as_float(u << 16);
            accy += __uint_as_float(u & 0xffff0000u);
        }
        __syncthreads();  // a1s free (W2 staged / previous gemm2 done)
        a1s[r][sub * 2 + 0] = fmaxf(dn * accx + bb.x, 0.f);
        a1s[r][sub * 2 + 1] = fmaxf(dn * accy + bb.y, 0.f);
        __syncthreads();

        // fused gemm2: thread (r, o=sub): hs2[node][o] = dn * sum_k a1s[r][k] * W2[k][o]
        float sum = 0.f;
#pragma unroll 8
        for (int k = 0; k < HID_C; ++k)
            sum += a1s[r][k] * W2s[k * OUT_C + sub];
        hs2b[node * OUT_C + sub] = f2bf(dn * sum);
    }
}

// ------- K6: gather layer 2 (bf16 hs2, prescaled) + epilogue -> out -------
// 256 thr, 8 nodes/block, 32 lanes/node (lane = out channel).

__global__ __launch_bounds__(256) void k_gather2(const int* __restrict__ row_start,
                                                 const int* __restrict__ eidx,
                                                 const ushort* __restrict__ hs2b,
                                                 const float* __restrict__ dinv,
                                                 const float* __restrict__ b2,
                                                 float* __restrict__ out) {
    int t = threadIdx.x;
    int sub = t & 31;
    int node = blockIdx.x * 8 + (t >> 5);  // N_NODES divisible by 8

    float dn = dinv[node];
    int rs = row_start[node];
    int re = row_start[node + 1];
    float acc = bf2f(hs2b[node * OUT_C + sub]);  // self loop
    int j = rs;
    for (; j + 7 < re; j += 8) {
        int s0 = eidx[j],     s1 = eidx[j + 1], s2 = eidx[j + 2], s3 = eidx[j + 3];
        int s4 = eidx[j + 4], s5 = eidx[j + 5], s6 = eidx[j + 6], s7 = eidx[j + 7];
        float v0 = bf2f(hs2b[s0 * OUT_C + sub]);
        float v1 = bf2f(hs2b[s1 * OUT_C + sub]);
        float v2 = bf2f(hs2b[s2 * OUT_C + sub]);
        float v3 = bf2f(hs2b[s3 * OUT_C + sub]);
        float v4 = bf2f(hs2b[s4 * OUT_C + sub]);
        float v5 = bf2f(hs2b[s5 * OUT_C + sub]);
        float v6 = bf2f(hs2b[s6 * OUT_C + sub]);
        float v7 = bf2f(hs2b[s7 * OUT_C + sub]);
        acc += ((v0 + v1) + (v2 + v3)) + ((v4 + v5) + (v6 + v7));
    }
    for (; j + 3 < re; j += 4) {
        int s0 = eidx[j], s1 = eidx[j + 1], s2 = eidx[j + 2], s3 = eidx[j + 3];
        float v0 = bf2f(hs2b[s0 * OUT_C + sub]);
        float v1 = bf2f(hs2b[s1 * OUT_C + sub]);
        float v2 = bf2f(hs2b[s2 * OUT_C + sub]);
        float v3 = bf2f(hs2b[s3 * OUT_C + sub]);
        acc += (v0 + v1) + (v2 + v3);
    }
    for (; j < re; ++j) acc += bf2f(hs2b[eidx[j] * OUT_C + sub]);

    out[node * OUT_C + sub] = dn * acc + b2[sub];
}

extern "C" void kernel_launch(void* const* d_in, const int* in_sizes, int n_in,
                              void* d_out, int out_size, void* d_ws, size_t ws_size,
                              hipStream_t stream) {
    const float* x  = (const float*)d_in[0];
    const int* ei   = (const int*)d_in[1];   // [2, E]: src then dst
    const float* W1 = (const float*)d_in[2];
    const float* b1 = (const float*)d_in[3];
    const float* W2 = (const float*)d_in[4];
    const float* b2 = (const float*)d_in[5];
    float* out = (float*)d_out;

    const int* src = ei;
    const int* dst = ei + N_EDGES;

    // workspace layout (bytes), total ~34.9 MB
    char* ws = (char*)d_ws;
    int*    row_start    = (int*)(ws + 0);            //   400,128 (N+1 ints)
    float*  dinv         = (float*)(ws + 400128);     //   400,128
    int*    bucket_start = (int*)(ws + 800256);       //     4,096
    int*    total        = (int*)(ws + 804352);       //     4,096
    int*    bcnt         = (int*)(ws + 808448);       // 1,048,576
    int*    off          = (int*)(ws + 1857024);      // 1,048,576
    int*    eidx         = (int*)(ws + 2905600);      // 6,400,000
    int*    tmp          = (int*)(ws + 9305600);      // 6,400,000
    ushort* h1b          = (ushort*)(ws + 15705600);  // 12,800,000 (bf16)
    ushort* hs2b         = (ushort*)(ws + 28505600);  //  6,400,000 (bf16)

    k_bucket_count<<<NBLK_B, 256, 0, stream>>>(dst, bcnt);
    k_col_scan<<<NBUCK, 256, 0, stream>>>(bcnt, off, total);
    k_bucket_scan<<<1, 256, 0, stream>>>(total, bucket_start, row_start);

    k_scatter_fat<<<NBLK_B + MF_BLKS, 256, 0, stream>>>(src, dst, bucket_start, off,
                                                        tmp, x, W1, h1b);
    k_csr_build<<<NBUCK, 256, 0, stream>>>(bucket_start, tmp, row_start, eidx, dinv,
                                           (uint*)h1b);

    k_gather1f<<<N_NODES / 32, 256, 0, stream>>>(row_start, eidx, (const uint*)h1b,
                                                 dinv, b1, W2, hs2b);
    k_gather2<<<N_NODES / 8, 256, 0, stream>>>(row_start, eidx, hs2b, dinv, b2, out);
}